// Round 4
// baseline (245.140 us; speedup 1.0000x reference)
//
#include <hip/hip_runtime.h>
#include <hip/hip_bf16.h>
#include <stdint.h>

#define N_ROWS 50000
#define D 384
#define K 8
#define BATCH 512
#define NEGO 128
#define NEDGE 1024

typedef float f32x4 __attribute__((ext_vector_type(4)));
typedef short bf16x8 __attribute__((ext_vector_type(8)));

__device__ __forceinline__ float wave_reduce_sum(float v) {
#pragma unroll
    for (int d = 1; d < 64; d <<= 1) v += __shfl_xor(v, d);
    return v;
}

static __device__ __forceinline__ uint16_t f2bfbits(float f) {
    __hip_bfloat16 h = __float2bfloat16(f);
    union { __hip_bfloat16 h; uint16_t u; } cv;
    cv.h = h;
    return cv.u;
}

// ---------------------------------------------------------------------------
// Kernel A: normalize virtual rows, G = Vn Vn^T + eps I, invert 8x8.
// ---------------------------------------------------------------------------
__global__ __launch_bounds__(64) void prep_kernel(const float* __restrict__ virt,
                                                  float* __restrict__ Vn,
                                                  float* __restrict__ Ginv) {
    __shared__ float Vs[K * D];
    __shared__ float Gs[K * K];
    int tid = threadIdx.x;
    for (int t = tid; t < K * D; t += 64) Vs[t] = virt[t];
    __syncthreads();
    for (int k = 0; k < K; ++k) {
        float ss = 0.f;
        for (int t = tid; t < D; t += 64) { float v = Vs[k * D + t]; ss += v * v; }
        ss = wave_reduce_sum(ss);
        float inv = 1.0f / sqrtf(ss + 1e-12f);
        for (int t = tid; t < D; t += 64) {
            float v = Vs[k * D + t] * inv;
            Vs[k * D + t] = v;
            Vn[k * D + t] = v;
        }
        __syncthreads();
    }
    int k = tid >> 3, m = tid & 7;
    float g = 0.f;
    for (int j = 0; j < D; ++j) g += Vs[k * D + j] * Vs[m * D + j];
    if (k == m) g += 1e-4f;
    Gs[tid] = g;
    __syncthreads();
    if (tid == 0) {
        float A[K][K], I8[K][K];
        for (int a = 0; a < K; ++a)
            for (int b2 = 0; b2 < K; ++b2) {
                A[a][b2] = Gs[a * K + b2];
                I8[a][b2] = (a == b2) ? 1.f : 0.f;
            }
        for (int p = 0; p < K; ++p) {
            float piv = 1.0f / A[p][p];
            for (int j = 0; j < K; ++j) { A[p][j] *= piv; I8[p][j] *= piv; }
            for (int r = 0; r < K; ++r)
                if (r != p) {
                    float f = A[r][p];
                    for (int j = 0; j < K; ++j) {
                        A[r][j] -= f * A[p][j];
                        I8[r][j] -= f * I8[p][j];
                    }
                }
        }
        for (int a = 0; a < K; ++a)
            for (int b2 = 0; b2 < K; ++b2) Ginv[a * K + b2] = I8[a][b2];
    }
}

// ---------------------------------------------------------------------------
// Kernel B: projection removal + l2norm, bf16 out.
// 1 row per 16-lane group (float4/lane x 6 iters), 256-thread block = 16 rows.
// launch_bounds(256,4) caps VGPR at 128 -> 4 waves/SIMD (R2 post-mortem: the
// 2-rows/group version hit 180 VGPR -> 2 waves/SIMD -> latency-bound at 9.5%
// occupancy).
// Algebraic note: the ref's first l2norm cancels -- l2norm(s*emb - s*pk*Ginv*V)
// == l2norm(emb - pk*Ginv*V) for s>0 -- so no ss reduction / invn needed.
// ---------------------------------------------------------------------------
__global__ __launch_bounds__(256, 4) void local_kernel(const float* __restrict__ emb,
                                                       const float* __restrict__ Vn,
                                                       const float* __restrict__ Ginv,
                                                       __hip_bfloat16* __restrict__ outb) {
    __shared__ float Vs[K * D];
    __shared__ float Gs[K * K];
    int tid = threadIdx.x;
    for (int t = tid; t < K * D; t += 256) Vs[t] = Vn[t];
    if (tid < K * K) Gs[tid] = Ginv[tid];
    __syncthreads();
    const float4* Vs4 = (const float4*)Vs;

    int q = tid & 15;
    int grp = tid >> 4;  // 0..15
    size_t row = (size_t)blockIdx.x * 16 + grp;
    const float4* xs = (const float4*)(emb + row * D);

    float4 v[6];
#pragma unroll
    for (int t = 0; t < 6; ++t) v[t] = xs[q + 16 * t];

    float pk[K];
#pragma unroll
    for (int k = 0; k < K; ++k) pk[k] = 0.f;
#pragma unroll
    for (int t = 0; t < 6; ++t) {
        float4 a = v[t];
        int j = q + 16 * t;
#pragma unroll
        for (int k = 0; k < K; ++k) {
            float4 w = Vs4[k * 96 + j];
            pk[k] += a.x * w.x + a.y * w.y + a.z * w.z + a.w * w.w;
        }
    }
#pragma unroll
    for (int d = 1; d < 16; d <<= 1) {
#pragma unroll
        for (int k = 0; k < K; ++k) pk[k] += __shfl_xor(pk[k], d);
    }
    float coef[K];
#pragma unroll
    for (int k = 0; k < K; ++k) {
        float s = 0.f;
#pragma unroll
        for (int m = 0; m < K; ++m) s += pk[m] * Gs[m * K + k];
        coef[k] = s;
    }

    float rss = 0.f;
#pragma unroll
    for (int t = 0; t < 6; ++t) {
        int j = q + 16 * t;
        float4 r = v[t];
#pragma unroll
        for (int k = 0; k < K; ++k) {
            float4 w = Vs4[k * 96 + j];
            r.x -= coef[k] * w.x; r.y -= coef[k] * w.y;
            r.z -= coef[k] * w.z; r.w -= coef[k] * w.w;
        }
        v[t] = r;
        rss += r.x * r.x + r.y * r.y + r.z * r.z + r.w * r.w;
    }
#pragma unroll
    for (int d = 1; d < 16; d <<= 1) rss += __shfl_xor(rss, d);
    float invr = 1.0f / sqrtf(rss + 1e-12f);
#pragma unroll
    for (int t = 0; t < 6; ++t) {
        int j = q + 16 * t;
        ushort4 p;
        p.x = f2bfbits(v[t].x * invr); p.y = f2bfbits(v[t].y * invr);
        p.z = f2bfbits(v[t].z * invr); p.w = f2bfbits(v[t].w * invr);
        *reinterpret_cast<ushort4*>(outb + row * D + (size_t)j * 4) = p;
    }
}

// ---------------------------------------------------------------------------
// Kernel C (MFMA): per ego-graph: gather X (bf16) into swizzled LDS,
// sim = X X^T via mfma_f32_16x16x32_bf16 (wave w owns rows 16w..16w+15),
// fused gumbel softmax + adjacency-bitmask diff + per-batch score.
// ---------------------------------------------------------------------------
__global__ __launch_bounds__(512) void batch_kernel(const __hip_bfloat16* __restrict__ localb,
                                                    const float* __restrict__ gumbel,
                                                    const int* __restrict__ idx_batch,
                                                    const int* __restrict__ edges_src,
                                                    const int* __restrict__ edges_dst,
                                                    float* __restrict__ scores) {
    __shared__ __hip_bfloat16 Xs[NEGO * D];  // 98304 B, swizzled
    __shared__ uint32_t adjmask[NEGO * 4];   // 2048 B
    __shared__ int idxs[NEGO];
    __shared__ float red[8];
    int tid = threadIdx.x;
    int b = blockIdx.x;
    if (tid < NEGO) idxs[tid] = idx_batch[b * NEGO + tid];
    adjmask[tid] = 0u;
    __syncthreads();

    {
        int row = tid >> 2, seg = tid & 3;
        const uint4* src = (const uint4*)(localb + (size_t)idxs[row] * D);
        char* dstbase = (char*)Xs;
#pragma unroll
        for (int i = 0; i < 12; ++i) {
            int c = seg + 4 * i;
            uint4 v = src[c];
            int off = (row * 768 + c * 16) ^ ((row & 7) << 4);
            *(uint4*)(dstbase + off) = v;
        }
    }
    for (int e = tid; e < NEDGE; e += 512) {
        int s = edges_src[b * NEDGE + e];
        int dd = edges_dst[b * NEDGE + e];
        atomicOr(&adjmask[s * 4 + (dd >> 5)], 1u << (dd & 31));
    }

    int w = tid >> 6, l = tid & 63;
    int c15 = l & 15, g4 = l >> 4;

    float gpre[4][8];
    {
        const float* gb = gumbel + (size_t)b * NEGO * NEGO;
#pragma unroll
        for (int reg = 0; reg < 4; ++reg) {
            int row = w * 16 + g4 * 4 + reg;
#pragma unroll
            for (int t = 0; t < 8; ++t) gpre[reg][t] = gb[row * NEGO + 16 * t + c15];
        }
    }
    __syncthreads();

    f32x4 acc[8];
#pragma unroll
    for (int t = 0; t < 8; ++t) acc[t] = (f32x4){0.f, 0.f, 0.f, 0.f};
    const char* xb = (const char*)Xs;
    int ar = w * 16 + c15;
    int aswz = (ar & 7) << 4;
    for (int ks = 0; ks < 12; ++ks) {
        int kbyte = ks * 64 + g4 * 16;
        bf16x8 afrag = *(const bf16x8*)(xb + ((ar * 768 + kbyte) ^ aswz));
#pragma unroll
        for (int t = 0; t < 8; ++t) {
            int br = t * 16 + c15;
            bf16x8 bfrag = *(const bf16x8*)(xb + ((br * 768 + kbyte) ^ ((br & 7) << 4)));
            acc[t] = __builtin_amdgcn_mfma_f32_16x16x32_bf16(afrag, bfrag, acc[t], 0, 0, 0);
        }
    }

    float wave_score = 0.f;
#pragma unroll
    for (int reg = 0; reg < 4; ++reg) {
        int row = w * 16 + g4 * 4 + reg;
        float z[8];
#pragma unroll
        for (int t = 0; t < 8; ++t) {
            float s = acc[t][reg];
            int col = 16 * t + c15;
            if (col == row) s = -1e9f;
            z[t] = s + gpre[reg][t];
        }
        float m = z[0];
#pragma unroll
        for (int t = 1; t < 8; ++t) m = fmaxf(m, z[t]);
#pragma unroll
        for (int d = 1; d < 16; d <<= 1) m = fmaxf(m, __shfl_xor(m, d));
        float e[8], se = 0.f;
#pragma unroll
        for (int t = 0; t < 8; ++t) { e[t] = expf(z[t] - m); se += e[t]; }
#pragma unroll
        for (int d = 1; d < 16; d <<= 1) se += __shfl_xor(se, d);
        float inv = 1.0f / se;
        uint32_t am[4];
#pragma unroll
        for (int qq = 0; qq < 4; ++qq) am[qq] = adjmask[row * 4 + qq];
        float sq = 0.f;
#pragma unroll
        for (int t = 0; t < 8; ++t) {
            int col = 16 * t + c15;
            float a = (float)((am[col >> 5] >> (col & 31)) & 1u);
            float d0 = a - e[t] * inv;
            sq += d0 * d0;
        }
#pragma unroll
        for (int d = 1; d < 16; d <<= 1) sq += __shfl_xor(sq, d);
        wave_score += sqrtf(sq);
    }
    wave_score += __shfl_xor(wave_score, 16);
    wave_score += __shfl_xor(wave_score, 32);
    if (l == 0) red[w] = wave_score;
    __syncthreads();
    if (tid == 0) {
        float tot = 0.f;
#pragma unroll
        for (int ww = 0; ww < 8; ++ww) tot += red[ww];
        scores[b] = tot * (1.0f / (float)NEGO);
    }
}

// ---------------------------------------------------------------------------
// Kernel D: min-max normalize scores, BCE loss.
// ---------------------------------------------------------------------------
__global__ __launch_bounds__(512) void finalize_kernel(const float* __restrict__ scores,
                                                       const int* __restrict__ labels,
                                                       float* __restrict__ out) {
    __shared__ float rmn[8], rmx[8], rsum[8];
    int tid = threadIdx.x, w = tid >> 6, l = tid & 63;
    float s = scores[tid];
    float mn = s, mx = s;
#pragma unroll
    for (int d = 1; d < 64; d <<= 1) {
        mn = fminf(mn, __shfl_xor(mn, d));
        mx = fmaxf(mx, __shfl_xor(mx, d));
    }
    if (l == 0) { rmn[w] = mn; rmx[w] = mx; }
    __syncthreads();
    mn = rmn[0]; mx = rmx[0];
#pragma unroll
    for (int ww = 1; ww < 8; ++ww) {
        mn = fminf(mn, rmn[ww]);
        mx = fmaxf(mx, rmx[ww]);
    }
    float norm = (s - mn) / (mx - mn + 1e-8f);
    out[tid] = norm;
    float y = (float)labels[tid];
    float lp = fmaxf(logf(norm), -100.0f);
    float l1p = fmaxf(log1pf(-norm), -100.0f);
    float term = y * lp + (1.0f - y) * l1p;
    term = wave_reduce_sum(term);
    if (l == 0) rsum[w] = term;
    __syncthreads();
    if (tid == 0) {
        float tot = 0.f;
        for (int ww = 0; ww < 8; ++ww) tot += rsum[ww];
        out[BATCH] = -tot / (float)BATCH;
    }
}

extern "C" void kernel_launch(void* const* d_in, const int* in_sizes, int n_in,
                              void* d_out, int out_size, void* d_ws, size_t ws_size,
                              hipStream_t stream) {
    (void)in_sizes; (void)n_in; (void)out_size; (void)ws_size;
    const float* text = (const float*)d_in[0];
    const float* virt = (const float*)d_in[1];
    const float* gum = (const float*)d_in[2];
    const int* idxb = (const int*)d_in[3];
    const int* esrc = (const int*)d_in[4];
    const int* edst = (const int*)d_in[5];
    const int* label = (const int*)d_in[6];
    float* out = (float*)d_out;

    float* Vn = (float*)d_ws;
    float* Ginv = Vn + K * D;
    float* scores = Ginv + K * K;
    __hip_bfloat16* localb = (__hip_bfloat16*)(scores + BATCH);

    hipLaunchKernelGGL(prep_kernel, dim3(1), dim3(64), 0, stream, virt, Vn, Ginv);
    hipLaunchKernelGGL(local_kernel, dim3(N_ROWS / 16), dim3(256), 0, stream, text, Vn, Ginv, localb);
    hipLaunchKernelGGL(batch_kernel, dim3(BATCH), dim3(512), 0, stream, localb, gum, idxb, esrc, edst, scores);
    hipLaunchKernelGGL(finalize_kernel, dim3(1), dim3(512), 0, stream, scores, label, out);
}

// Round 5
// 79.630 us; speedup vs baseline: 3.0785x; 3.0785x over previous
//
#include <hip/hip_runtime.h>
#include <hip/hip_bf16.h>
#include <stdint.h>

#define N_ROWS 50000
#define D 384
#define K 8
#define BATCH 512
#define NEGO 128
#define NEDGE 1024

typedef float f32x4 __attribute__((ext_vector_type(4)));
typedef short bf16x8 __attribute__((ext_vector_type(8)));

__device__ __forceinline__ float wave_reduce_sum(float v) {
#pragma unroll
    for (int d = 1; d < 64; d <<= 1) v += __shfl_xor(v, d);
    return v;
}

static __device__ __forceinline__ uint16_t f2bfbits(float f) {
    __hip_bfloat16 h = __float2bfloat16(f);
    union { __hip_bfloat16 h; uint16_t u; } cv;
    cv.h = h;
    return cv.u;
}

// ---------------------------------------------------------------------------
// Kernel A: normalize virtual rows, G = Vn Vn^T + eps I, invert 8x8.
// ---------------------------------------------------------------------------
__global__ __launch_bounds__(64) void prep_kernel(const float* __restrict__ virt,
                                                  float* __restrict__ Vn,
                                                  float* __restrict__ Ginv) {
    __shared__ float Vs[K * D];
    __shared__ float Gs[K * K];
    int tid = threadIdx.x;
    for (int t = tid; t < K * D; t += 64) Vs[t] = virt[t];
    __syncthreads();
    for (int k = 0; k < K; ++k) {
        float ss = 0.f;
        for (int t = tid; t < D; t += 64) { float v = Vs[k * D + t]; ss += v * v; }
        ss = wave_reduce_sum(ss);
        float inv = 1.0f / sqrtf(ss + 1e-12f);
        for (int t = tid; t < D; t += 64) {
            float v = Vs[k * D + t] * inv;
            Vs[k * D + t] = v;
            Vn[k * D + t] = v;
        }
        __syncthreads();
    }
    int k = tid >> 3, m = tid & 7;
    float g = 0.f;
    for (int j = 0; j < D; ++j) g += Vs[k * D + j] * Vs[m * D + j];
    if (k == m) g += 1e-4f;
    Gs[tid] = g;
    __syncthreads();
    if (tid == 0) {
        float A[K][K], I8[K][K];
        for (int a = 0; a < K; ++a)
            for (int b2 = 0; b2 < K; ++b2) {
                A[a][b2] = Gs[a * K + b2];
                I8[a][b2] = (a == b2) ? 1.f : 0.f;
            }
        for (int p = 0; p < K; ++p) {
            float piv = 1.0f / A[p][p];
            for (int j = 0; j < K; ++j) { A[p][j] *= piv; I8[p][j] *= piv; }
            for (int r = 0; r < K; ++r)
                if (r != p) {
                    float f = A[r][p];
                    for (int j = 0; j < K; ++j) {
                        A[r][j] -= f * A[p][j];
                        I8[r][j] -= f * I8[p][j];
                    }
                }
        }
        for (int a = 0; a < K; ++a)
            for (int b2 = 0; b2 < K; ++b2) Ginv[a * K + b2] = I8[a][b2];
    }
}

// ---------------------------------------------------------------------------
// Kernel B: projection removal + l2norm, bf16 out.
// 1 row per 16-lane group, 256-thread block = 16 rows, float4 loads.
// R3 post-mortem: __launch_bounds__(256,4) forced VGPR=64 -> scratch spill
// (WRITE_SIZE 509MB). Fix: no min-waves hint; instead reduce pressure
// structurally -- phase 1 computes pk and DISCARDS the row, phase 2 re-loads
// it (emb is 76.8MB < 256MB L3, re-read ~us later = L3 hit, not HBM).
// asm memory clobber between phases stops the compiler CSE-ing the loads
// back into one live value.
// Algebra: the ref's first l2norm cancels (scale-invariance of the final
// l2norm), so no ss/invn.
// ---------------------------------------------------------------------------
__global__ __launch_bounds__(256) void local_kernel(const float* __restrict__ emb,
                                                    const float* __restrict__ Vn,
                                                    const float* __restrict__ Ginv,
                                                    __hip_bfloat16* __restrict__ outb) {
    __shared__ float Vs[K * D];
    __shared__ float Gs[K * K];
    int tid = threadIdx.x;
    for (int t = tid; t < K * D; t += 256) Vs[t] = Vn[t];
    if (tid < K * K) Gs[tid] = Ginv[tid];
    __syncthreads();
    const float4* Vs4 = (const float4*)Vs;

    int q = tid & 15;
    int grp = tid >> 4;  // 0..15
    size_t row = (size_t)blockIdx.x * 16 + grp;
    const float4* xs = (const float4*)(emb + row * D);

    // ---- phase 1: pk[k] = x . v_k (row chunks discarded after use) ----
    float pk[K];
#pragma unroll
    for (int k = 0; k < K; ++k) pk[k] = 0.f;
#pragma unroll
    for (int t = 0; t < 6; ++t) {
        float4 a = xs[q + 16 * t];
        int j = q + 16 * t;
#pragma unroll
        for (int k = 0; k < K; ++k) {
            float4 w = Vs4[k * 96 + j];
            pk[k] += a.x * w.x + a.y * w.y + a.z * w.z + a.w * w.w;
        }
    }
#pragma unroll
    for (int d = 1; d < 16; d <<= 1) {
#pragma unroll
        for (int k = 0; k < K; ++k) pk[k] += __shfl_xor(pk[k], d);
    }
    float coef[K];
#pragma unroll
    for (int k = 0; k < K; ++k) {
        float s = 0.f;
#pragma unroll
        for (int m = 0; m < K; ++m) s += pk[m] * Gs[m * K + k];
        coef[k] = s;
    }

    // force re-load in phase 2 (no CSE back to long-lived registers)
    asm volatile("" ::: "memory");

    // ---- phase 2: residual, rss, scale, store ----
    float4 r[6];
    float rss = 0.f;
#pragma unroll
    for (int t = 0; t < 6; ++t) {
        int j = q + 16 * t;
        float4 a = xs[j];
#pragma unroll
        for (int k = 0; k < K; ++k) {
            float4 w = Vs4[k * 96 + j];
            a.x -= coef[k] * w.x; a.y -= coef[k] * w.y;
            a.z -= coef[k] * w.z; a.w -= coef[k] * w.w;
        }
        r[t] = a;
        rss += a.x * a.x + a.y * a.y + a.z * a.z + a.w * a.w;
    }
#pragma unroll
    for (int d = 1; d < 16; d <<= 1) rss += __shfl_xor(rss, d);
    float invr = 1.0f / sqrtf(rss + 1e-12f);
#pragma unroll
    for (int t = 0; t < 6; ++t) {
        int j = q + 16 * t;
        ushort4 p;
        p.x = f2bfbits(r[t].x * invr); p.y = f2bfbits(r[t].y * invr);
        p.z = f2bfbits(r[t].z * invr); p.w = f2bfbits(r[t].w * invr);
        *reinterpret_cast<ushort4*>(outb + row * D + (size_t)j * 4) = p;
    }
}

// ---------------------------------------------------------------------------
// Kernel C (MFMA): per ego-graph: gather X (bf16) into swizzled LDS,
// sim = X X^T via mfma_f32_16x16x32_bf16 (wave w owns rows 16w..16w+15),
// fused gumbel softmax + adjacency-bitmask diff + per-batch score.
// ---------------------------------------------------------------------------
__global__ __launch_bounds__(512) void batch_kernel(const __hip_bfloat16* __restrict__ localb,
                                                    const float* __restrict__ gumbel,
                                                    const int* __restrict__ idx_batch,
                                                    const int* __restrict__ edges_src,
                                                    const int* __restrict__ edges_dst,
                                                    float* __restrict__ scores) {
    __shared__ __hip_bfloat16 Xs[NEGO * D];  // 98304 B, swizzled
    __shared__ uint32_t adjmask[NEGO * 4];   // 2048 B
    __shared__ int idxs[NEGO];
    __shared__ float red[8];
    int tid = threadIdx.x;
    int b = blockIdx.x;
    if (tid < NEGO) idxs[tid] = idx_batch[b * NEGO + tid];
    adjmask[tid] = 0u;
    __syncthreads();

    {
        int row = tid >> 2, seg = tid & 3;
        const uint4* src = (const uint4*)(localb + (size_t)idxs[row] * D);
        char* dstbase = (char*)Xs;
#pragma unroll
        for (int i = 0; i < 12; ++i) {
            int c = seg + 4 * i;
            uint4 v = src[c];
            int off = (row * 768 + c * 16) ^ ((row & 7) << 4);
            *(uint4*)(dstbase + off) = v;
        }
    }
    for (int e = tid; e < NEDGE; e += 512) {
        int s = edges_src[b * NEDGE + e];
        int dd = edges_dst[b * NEDGE + e];
        atomicOr(&adjmask[s * 4 + (dd >> 5)], 1u << (dd & 31));
    }

    int w = tid >> 6, l = tid & 63;
    int c15 = l & 15, g4 = l >> 4;

    float gpre[4][8];
    {
        const float* gb = gumbel + (size_t)b * NEGO * NEGO;
#pragma unroll
        for (int reg = 0; reg < 4; ++reg) {
            int row = w * 16 + g4 * 4 + reg;
#pragma unroll
            for (int t = 0; t < 8; ++t) gpre[reg][t] = gb[row * NEGO + 16 * t + c15];
        }
    }
    __syncthreads();

    f32x4 acc[8];
#pragma unroll
    for (int t = 0; t < 8; ++t) acc[t] = (f32x4){0.f, 0.f, 0.f, 0.f};
    const char* xb = (const char*)Xs;
    int ar = w * 16 + c15;
    int aswz = (ar & 7) << 4;
    for (int ks = 0; ks < 12; ++ks) {
        int kbyte = ks * 64 + g4 * 16;
        bf16x8 afrag = *(const bf16x8*)(xb + ((ar * 768 + kbyte) ^ aswz));
#pragma unroll
        for (int t = 0; t < 8; ++t) {
            int br = t * 16 + c15;
            bf16x8 bfrag = *(const bf16x8*)(xb + ((br * 768 + kbyte) ^ ((br & 7) << 4)));
            acc[t] = __builtin_amdgcn_mfma_f32_16x16x32_bf16(afrag, bfrag, acc[t], 0, 0, 0);
        }
    }

    float wave_score = 0.f;
#pragma unroll
    for (int reg = 0; reg < 4; ++reg) {
        int row = w * 16 + g4 * 4 + reg;
        float z[8];
#pragma unroll
        for (int t = 0; t < 8; ++t) {
            float s = acc[t][reg];
            int col = 16 * t + c15;
            if (col == row) s = -1e9f;
            z[t] = s + gpre[reg][t];
        }
        float m = z[0];
#pragma unroll
        for (int t = 1; t < 8; ++t) m = fmaxf(m, z[t]);
#pragma unroll
        for (int d = 1; d < 16; d <<= 1) m = fmaxf(m, __shfl_xor(m, d));
        float e[8], se = 0.f;
#pragma unroll
        for (int t = 0; t < 8; ++t) { e[t] = expf(z[t] - m); se += e[t]; }
#pragma unroll
        for (int d = 1; d < 16; d <<= 1) se += __shfl_xor(se, d);
        float inv = 1.0f / se;
        uint32_t am[4];
#pragma unroll
        for (int qq = 0; qq < 4; ++qq) am[qq] = adjmask[row * 4 + qq];
        float sq = 0.f;
#pragma unroll
        for (int t = 0; t < 8; ++t) {
            int col = 16 * t + c15;
            float a = (float)((am[col >> 5] >> (col & 31)) & 1u);
            float d0 = a - e[t] * inv;
            sq += d0 * d0;
        }
#pragma unroll
        for (int d = 1; d < 16; d <<= 1) sq += __shfl_xor(sq, d);
        wave_score += sqrtf(sq);
    }
    wave_score += __shfl_xor(wave_score, 16);
    wave_score += __shfl_xor(wave_score, 32);
    if (l == 0) red[w] = wave_score;
    __syncthreads();
    if (tid == 0) {
        float tot = 0.f;
#pragma unroll
        for (int ww = 0; ww < 8; ++ww) tot += red[ww];
        scores[b] = tot * (1.0f / (float)NEGO);
    }
}

// ---------------------------------------------------------------------------
// Kernel D: min-max normalize scores, BCE loss.
// ---------------------------------------------------------------------------
__global__ __launch_bounds__(512) void finalize_kernel(const float* __restrict__ scores,
                                                       const int* __restrict__ labels,
                                                       float* __restrict__ out) {
    __shared__ float rmn[8], rmx[8], rsum[8];
    int tid = threadIdx.x, w = tid >> 6, l = tid & 63;
    float s = scores[tid];
    float mn = s, mx = s;
#pragma unroll
    for (int d = 1; d < 64; d <<= 1) {
        mn = fminf(mn, __shfl_xor(mn, d));
        mx = fmaxf(mx, __shfl_xor(mx, d));
    }
    if (l == 0) { rmn[w] = mn; rmx[w] = mx; }
    __syncthreads();
    mn = rmn[0]; mx = rmx[0];
#pragma unroll
    for (int ww = 1; ww < 8; ++ww) {
        mn = fminf(mn, rmn[ww]);
        mx = fmaxf(mx, rmx[ww]);
    }
    float norm = (s - mn) / (mx - mn + 1e-8f);
    out[tid] = norm;
    float y = (float)labels[tid];
    float lp = fmaxf(logf(norm), -100.0f);
    float l1p = fmaxf(log1pf(-norm), -100.0f);
    float term = y * lp + (1.0f - y) * l1p;
    term = wave_reduce_sum(term);
    if (l == 0) rsum[w] = term;
    __syncthreads();
    if (tid == 0) {
        float tot = 0.f;
        for (int ww = 0; ww < 8; ++ww) tot += rsum[ww];
        out[BATCH] = -tot / (float)BATCH;
    }
}

extern "C" void kernel_launch(void* const* d_in, const int* in_sizes, int n_in,
                              void* d_out, int out_size, void* d_ws, size_t ws_size,
                              hipStream_t stream) {
    (void)in_sizes; (void)n_in; (void)out_size; (void)ws_size;
    const float* text = (const float*)d_in[0];
    const float* virt = (const float*)d_in[1];
    const float* gum = (const float*)d_in[2];
    const int* idxb = (const int*)d_in[3];
    const int* esrc = (const int*)d_in[4];
    const int* edst = (const int*)d_in[5];
    const int* label = (const int*)d_in[6];
    float* out = (float*)d_out;

    float* Vn = (float*)d_ws;
    float* Ginv = Vn + K * D;
    float* scores = Ginv + K * K;
    __hip_bfloat16* localb = (__hip_bfloat16*)(scores + BATCH);

    hipLaunchKernelGGL(prep_kernel, dim3(1), dim3(64), 0, stream, virt, Vn, Ginv);
    hipLaunchKernelGGL(local_kernel, dim3(N_ROWS / 16), dim3(256), 0, stream, text, Vn, Ginv, localb);
    hipLaunchKernelGGL(batch_kernel, dim3(BATCH), dim3(512), 0, stream, localb, gum, idxb, esrc, edst, scores);
    hipLaunchKernelGGL(finalize_kernel, dim3(1), dim3(512), 0, stream, scores, label, out);
}